// Round 11
// baseline (360.363 us; speedup 1.0000x reference)
//
#include <hip/hip_runtime.h>
#include <hip/hip_bf16.h>

typedef __hip_bfloat16 bf16;
typedef unsigned short u16;
typedef short short8 __attribute__((ext_vector_type(8)));
typedef float f32x4 __attribute__((ext_vector_type(4)));

static constexpr int B_   = 8;
static constexpr int Lq_  = 10000;
static constexpr int C_   = 256;
static constexpr int NH_  = 8;
static constexpr int NP_  = 4;
static constexpr int HIMG = 100;
static constexpr int WIMG = 100;
static constexpr int LIN  = 10000;   // H*W

__device__ __forceinline__ u16 f2bf(float x) {
    union { bf16 b; u16 u; } cv; cv.b = __float2bfloat16(x); return cv.u;
}
__device__ __forceinline__ float bf2f(u16 u) {
    return __uint_as_float((unsigned)u << 16);
}

// Async global -> LDS, 16 B per lane. LDS dest wave-uniform; HW writes
// base + lane*16 (guide §5 m104).
__device__ __forceinline__ void gl_lds16(const void* g, void* l) {
    __builtin_amdgcn_global_load_lds(
        (const __attribute__((address_space(1))) void*)g,
        (__attribute__((address_space(3))) void*)l, 16, 0, 0);
}
__device__ __forceinline__ void drain_barrier() {
    asm volatile("s_waitcnt vmcnt(0) lgkmcnt(0)" ::: "memory");
    __builtin_amdgcn_s_barrier();
}

// ---------------------------------------------------------------------------
// gemm256 v2 — the one GEMM engine. C[M][ldc](@ col n0) = A[M][K] @ B + bias.
// 128x256 tile, 8 waves (2m x 4n), BK=64, 2-phase dbuf, 2 blocks/CU.
// B pre-formatted [N][K]: Bg[n][kd] = W[(kd&~63)|((kd&63)^((n&7)<<3))][n].
// N-tiling: n0 = blockIdx.y*256 (B rows offset, bias/store col offset).
// AMODE: 0 = A f32 (reg-stage+convert)
//        1 = A bf16 linear (gl_lds, source-side XOR swizzle)
//        2 = A bf16 PRE-SWIZZLED q1b-format (verbatim gl_lds copy)
// EPI:   0 = bias -> bf16 linear
//        1 = bias+relu -> bf16 linear
//        2 = LN(resid f32) -> SWIZZLED bf16 (q1b format)   [gridDim.y==1]
//        3 = LN(resid swz-bf16) -> f32 linear              [gridDim.y==1]
// ---------------------------------------------------------------------------
template <int AMODE, int EPI>
__global__ __launch_bounds__(512, 2) void gemm256(
    const void* __restrict__ Av, const u16* __restrict__ Bg,
    const float* __restrict__ bias, const void* __restrict__ resid,
    const float* __restrict__ gw, const float* __restrict__ bw,
    void* __restrict__ Cv, int K, int ldc)
{
    __shared__ __align__(16) u16 At[2][128 * 64];
    __shared__ __align__(16) u16 Bt[2][256 * 64];
    __shared__ float red[2][128][4];

    const int tid  = threadIdx.x;
    const int lane = tid & 63;
    const int w    = tid >> 6;
    const int wm   = w >> 2, wn = w & 3;
    const int m0   = blockIdx.x * 128;
    const int n0   = blockIdx.y * 256;
    const u16* BgB = Bg + (size_t)n0 * K;

    f32x4 acc[4][4];
#pragma unroll
    for (int i = 0; i < 4; ++i)
#pragma unroll
        for (int j = 0; j < 4; ++j) acc[i][j] = f32x4{0.f, 0.f, 0.f, 0.f};

    auto stageA = [&](int t) {
        const int kt = t << 6;
        if constexpr (AMODE == 0) {
            const int row = tid >> 2;
            const int k0  = (tid & 3) << 4;
            const float* s = (const float*)Av + (size_t)(m0 + row) * K + kt + k0;
            float4 v0 = *(const float4*)(s + 0);
            float4 v1 = *(const float4*)(s + 4);
            float4 v2 = *(const float4*)(s + 8);
            float4 v3 = *(const float4*)(s + 12);
            union { short8 s8; u16 u[8]; } ga, gb;
            ga.u[0]=f2bf(v0.x); ga.u[1]=f2bf(v0.y); ga.u[2]=f2bf(v0.z); ga.u[3]=f2bf(v0.w);
            ga.u[4]=f2bf(v1.x); ga.u[5]=f2bf(v1.y); ga.u[6]=f2bf(v1.z); ga.u[7]=f2bf(v1.w);
            gb.u[0]=f2bf(v2.x); gb.u[1]=f2bf(v2.y); gb.u[2]=f2bf(v2.z); gb.u[3]=f2bf(v2.w);
            gb.u[4]=f2bf(v3.x); gb.u[5]=f2bf(v3.y); gb.u[6]=f2bf(v3.z); gb.u[7]=f2bf(v3.w);
            u16* d = &At[t & 1][row * 64];
            *(short8*)&d[(k0)     ^ ((row & 7) << 3)] = ga.s8;
            *(short8*)&d[(k0 + 8) ^ ((row & 7) << 3)] = gb.s8;
        } else if constexpr (AMODE == 1) {
#pragma unroll
            for (int i = 0; i < 2; ++i) {
                const int rb  = w * 16 + i * 8;
                const int row = rb + (lane >> 3);
                const int gs  = (lane & 7) ^ (row & 7);
                gl_lds16((const u16*)Av + (size_t)(m0 + row) * K + kt + gs * 8,
                         &At[t & 1][rb * 64]);
            }
        } else {   // AMODE == 2: pre-swizzled, verbatim copy
#pragma unroll
            for (int i = 0; i < 2; ++i) {
                const int rb  = w * 16 + i * 8;
                const int row = rb + (lane >> 3);
                gl_lds16((const u16*)Av + (size_t)(m0 + row) * K + kt + (lane & 7) * 8,
                         &At[t & 1][rb * 64]);
            }
        }
    };
    auto stageB = [&](int t) {
        const int kt = t << 6;
#pragma unroll
        for (int i = 0; i < 4; ++i) {
            const int rb  = w * 32 + i * 8;
            const int row = rb + (lane >> 3);
            gl_lds16(BgB + (size_t)row * K + kt + (lane & 7) * 8,
                     &Bt[t & 1][rb * 64]);
        }
    };
    auto compute = [&](int t) {
        const u16* a = At[t & 1];
        const u16* b = Bt[t & 1];
#pragma unroll
        for (int ks = 0; ks < 2; ++ks) {
            const int ko = ks * 32 + ((lane >> 4) << 3);
            short8 bfr[4];
#pragma unroll
            for (int n = 0; n < 4; ++n) {
                const int nr = wn * 64 + n * 16 + (lane & 15);
                bfr[n] = *(const short8*)&b[nr * 64 + (ko ^ ((nr & 7) << 3))];
            }
#pragma unroll
            for (int m = 0; m < 4; ++m) {
                const int ar = wm * 64 + m * 16 + (lane & 15);
                const short8 af = *(const short8*)&a[ar * 64 + (ko ^ ((ar & 7) << 3))];
#pragma unroll
                for (int n = 0; n < 4; ++n)
                    acc[m][n] = __builtin_amdgcn_mfma_f32_16x16x32_bf16(
                        af, bfr[n], acc[m][n], 0, 0, 0);
            }
        }
    };

    stageA(0); stageB(0);
    drain_barrier();
    const int nt = K >> 6;
    for (int t = 0; t < nt; ++t) {
        if (t + 1 < nt) { stageA(t + 1); stageB(t + 1); }
        compute(t);
        drain_barrier();
    }

    float bcol[4], gcol[4], becol[4];
#pragma unroll
    for (int n = 0; n < 4; ++n) {
        const int col = wn * 64 + n * 16 + (lane & 15);
        bcol[n] = bias[n0 + col];
        if (EPI >= 2) { gcol[n] = gw[col]; becol[n] = bw[col]; }
    }

    if constexpr (EPI <= 1) {
        u16* Co = (u16*)Cv;
#pragma unroll
        for (int m = 0; m < 4; ++m)
#pragma unroll
            for (int r = 0; r < 4; ++r) {
                const int lr = wm * 64 + m * 16 + (lane >> 4) * 4 + r;
#pragma unroll
                for (int n = 0; n < 4; ++n) {
                    const int col = wn * 64 + n * 16 + (lane & 15);
                    float v = acc[m][n][r] + bcol[n];
                    if (EPI == 1) v = fmaxf(v, 0.f);
                    Co[(size_t)(m0 + lr) * ldc + n0 + col] = f2bf(v);
                }
            }
    } else {
        // LN epilogue (gridDim.y == 1): v = acc + bias + resid
        float s[4][4], s2[4][4];
#pragma unroll
        for (int m = 0; m < 4; ++m)
#pragma unroll
            for (int r = 0; r < 4; ++r) {
                const int lr = wm * 64 + m * 16 + (lane >> 4) * 4 + r;
                float ps = 0.f, ps2 = 0.f;
#pragma unroll
                for (int n = 0; n < 4; ++n) {
                    const int col = wn * 64 + n * 16 + (lane & 15);
                    float rv;
                    if constexpr (EPI == 2)
                        rv = ((const float*)resid)[(size_t)(m0 + lr) * 256 + col];
                    else
                        rv = bf2f(((const u16*)resid)[(size_t)(m0 + lr) * 256
                                                      + (col ^ ((lr & 7) << 3))]);
                    float v = acc[m][n][r] + bcol[n] + rv;
                    acc[m][n][r] = v;
                    ps += v; ps2 += v * v;
                }
#pragma unroll
                for (int o = 1; o < 16; o <<= 1) {
                    ps  += __shfl_xor(ps,  o);
                    ps2 += __shfl_xor(ps2, o);
                }
                s[m][r] = ps; s2[m][r] = ps2;
            }
        if ((lane & 15) == 0) {
#pragma unroll
            for (int m = 0; m < 4; ++m)
#pragma unroll
                for (int r = 0; r < 4; ++r) {
                    const int lr = wm * 64 + m * 16 + (lane >> 4) * 4 + r;
                    red[0][lr][wn] = s[m][r];
                    red[1][lr][wn] = s2[m][r];
                }
        }
        __syncthreads();
        if (tid < 128) {
            const float ss  = red[0][tid][0] + red[0][tid][1] + red[0][tid][2] + red[0][tid][3];
            const float ss2 = red[1][tid][0] + red[1][tid][1] + red[1][tid][2] + red[1][tid][3];
            const float mean = ss * (1.f / 256.f);
            const float var  = fmaxf(ss2 * (1.f / 256.f) - mean * mean, 0.f);
            red[0][tid][0] = mean;
            red[1][tid][0] = rsqrtf(var + 1e-5f);
        }
        __syncthreads();
#pragma unroll
        for (int m = 0; m < 4; ++m)
#pragma unroll
            for (int r = 0; r < 4; ++r) {
                const int lr = wm * 64 + m * 16 + (lane >> 4) * 4 + r;
                const float mean = red[0][lr][0];
                const float rstd = red[1][lr][0];
#pragma unroll
                for (int n = 0; n < 4; ++n) {
                    const int col = wn * 64 + n * 16 + (lane & 15);
                    const float o = (acc[m][n][r] - mean) * rstd * gcol[n] + becol[n];
                    if constexpr (EPI == 2)
                        ((u16*)Cv)[(size_t)(m0 + lr) * 256 + (col ^ ((lr & 7) << 3))] = f2bf(o);
                    else
                        ((float*)Cv)[(size_t)(m0 + lr) * 256 + col] = o;
                }
            }
    }
}

// ---------------------------------------------------------------------------
// 4-wave 128x128 MFMA GEMM — oaw projection only (unchanged).
// ---------------------------------------------------------------------------
__global__ __launch_bounds__(256) void gemm_oaw(
    const float* __restrict__ Av, const u16* __restrict__ Bt,
    const float* __restrict__ bias, float* __restrict__ C,
    int M, int K, int Nreal, int ldc)
{
    __shared__ __align__(16) u16 Asl[2][128 * 32];
    __shared__ __align__(16) u16 Bsl[2][128 * 32];

    const int tid  = threadIdx.x;
    const int lane = tid & 63;
    const int w    = tid >> 6;
    const int wr   = (w >> 1) * 64;
    const int wc   = (w & 1) * 64;
    const int m0   = blockIdx.y * 128;
    const int n0   = blockIdx.x * 128;

    const int srow = lane >> 2;
    const int scol = (lane & 3) << 3;
    const u16* bG = Bt + (size_t)(n0 + w * 32 + srow) * K + scol;
    const size_t rstep16 = (size_t)16 * K;

    const int ar  = lane >> 3;
    const int ac  = (lane & 7) << 2;
    const float* aGf = Av + (size_t)(m0 + w * 32 + ar) * K + ac;

    const int aRoff = (wr + (lane & 15)) * 32 + (lane >> 4) * 8;
    const int bRoff = (wc + (lane & 15)) * 32 + (lane >> 4) * 8;

    f32x4 acc[4][4];
#pragma unroll
    for (int i = 0; i < 4; ++i)
#pragma unroll
        for (int j = 0; j < 4; ++j) acc[i][j] = f32x4{0.f, 0.f, 0.f, 0.f};

    float4 a4[4];
    const int nt = K >> 5;

#pragma unroll
    for (int rep = 0; rep < 4; ++rep)
        a4[rep] = *(const float4*)(aGf + (size_t)(rep * 8) * K);
#pragma unroll
    for (int rep = 0; rep < 4; ++rep) {
        ushort4 v{f2bf(a4[rep].x), f2bf(a4[rep].y), f2bf(a4[rep].z), f2bf(a4[rep].w)};
        *(ushort4*)&Asl[0][(w * 32 + rep * 8 + ar) * 32 + ac] = v;
    }
    gl_lds16(bG, &Bsl[0][(w * 32) * 32]);
    gl_lds16(bG + rstep16, &Bsl[0][(w * 32 + 16) * 32]);
    drain_barrier();

    for (int t = 0; t < nt; ++t) {
        const int cur = t & 1, nxt = cur ^ 1;
        const int k0n = (t + 1) << 5;
        const bool has_next = (t + 1 < nt);
        if (has_next) {
#pragma unroll
            for (int rep = 0; rep < 4; ++rep)
                a4[rep] = *(const float4*)(aGf + k0n + (size_t)(rep * 8) * K);
            gl_lds16(bG + k0n, &Bsl[nxt][(w * 32) * 32]);
            gl_lds16(bG + k0n + rstep16, &Bsl[nxt][(w * 32 + 16) * 32]);
        }
        short8 af[4], bfr[4];
#pragma unroll
        for (int m = 0; m < 4; ++m) af[m]  = *(const short8*)&Asl[cur][aRoff + m * 16 * 32];
#pragma unroll
        for (int n = 0; n < 4; ++n) bfr[n] = *(const short8*)&Bsl[cur][bRoff + n * 16 * 32];
#pragma unroll
        for (int m = 0; m < 4; ++m)
#pragma unroll
            for (int n = 0; n < 4; ++n)
                acc[m][n] = __builtin_amdgcn_mfma_f32_16x16x32_bf16(
                    af[m], bfr[n], acc[m][n], 0, 0, 0);
        if (has_next) {
#pragma unroll
            for (int rep = 0; rep < 4; ++rep) {
                ushort4 v{f2bf(a4[rep].x), f2bf(a4[rep].y), f2bf(a4[rep].z), f2bf(a4[rep].w)};
                *(ushort4*)&Asl[nxt][(w * 32 + rep * 8 + ar) * 32 + ac] = v;
            }
        }
        drain_barrier();
    }

#pragma unroll
    for (int n = 0; n < 4; ++n) {
        const int gc = n0 + wc + n * 16 + (lane & 15);
        if (gc >= Nreal) continue;
        const float bv = bias[gc];
        const int gr0 = m0 + wr + (lane >> 4) * 4;
#pragma unroll
        for (int m = 0; m < 4; ++m)
#pragma unroll
            for (int r = 0; r < 4; ++r)
                C[(size_t)(gr0 + m * 16 + r) * ldc + gc] = acc[m][n][r] + bv;
    }
}

// ---------------------------------------------------------------------------
// Weight prep — all B matrices in gemm256 [N][K] format:
//   Bg[n][kd] = W[(kd&~63) | ((kd&63) ^ ((n&7)<<3))][n]
// Wvs/Wos: N=256,K=256. W1g: N=1024,K=256. W2g: N=256,K=1024.
// Woa: linear [128][256] + padded bias (gemm_oaw format, unchanged).
// ---------------------------------------------------------------------------
__global__ __launch_bounds__(256) void prep_all(
    const float* __restrict__ Wv, const float* __restrict__ Wo,
    const float* __restrict__ W1, const float* __restrict__ W2,
    const float* __restrict__ Woff, const float* __restrict__ Waw,
    const float* __restrict__ boff, const float* __restrict__ baw,
    u16* __restrict__ Wvs, u16* __restrict__ Wos,
    u16* __restrict__ W1g, u16* __restrict__ W2g,
    u16* __restrict__ Woa, float* __restrict__ boa)
{
    const int idx = blockIdx.x * 256 + threadIdx.x;
    if (idx < 65536) {
        const int n = idx >> 8, kd = idx & 255;
        const int k = (kd & ~63) | ((kd & 63) ^ ((n & 7) << 3));
        Wvs[idx] = f2bf(Wv[(size_t)k * 256 + n]);
    } else if (idx < 131072) {
        const int i = idx - 65536, n = i >> 8, kd = i & 255;
        const int k = (kd & ~63) | ((kd & 63) ^ ((n & 7) << 3));
        Wos[i] = f2bf(Wo[(size_t)k * 256 + n]);
    } else if (idx < 393216) {
        const int i = idx - 131072, n = i >> 8, kd = i & 255;   // n: 0..1023
        const int k = (kd & ~63) | ((kd & 63) ^ ((n & 7) << 3));
        W1g[i] = f2bf(W1[(size_t)k * 1024 + n]);
    } else if (idx < 655360) {
        const int i = idx - 393216, n = i >> 10, kd = i & 1023; // k: 0..1023
        const int k = (kd & ~63) | ((kd & 63) ^ ((n & 7) << 3));
        W2g[i] = f2bf(W2[(size_t)k * 256 + n]);
    } else if (idx < 688128) {
        const int i = idx - 655360, n = i >> 8, k = i & 255;
        float v = 0.f;
        if (n < 64)      v = Woff[(size_t)k * 64 + n];
        else if (n < 96) v = Waw[(size_t)k * 32 + (n - 64)];
        Woa[i] = f2bf(v);
    } else if (idx < 688256) {
        const int i = idx - 688128;
        boa[i] = (i < 64) ? boff[i] : (i < 96 ? baw[i - 64] : 0.f);
    }
}

// ---------------------------------------------------------------------------
// Bilinear sampling + attention-weight combine (unchanged).
// ---------------------------------------------------------------------------
__global__ __launch_bounds__(256) void sample_attn(
    const u16* __restrict__ val, const float* __restrict__ oaw,
    const float* __restrict__ refp, u16* __restrict__ attn)
{
    const int t   = threadIdx.x;
    const int gid = blockIdx.x * 64 + (t >> 2);
    const int c0  = (t & 3) << 3;
    const int h   = gid & (NH_ - 1);
    const int bq  = gid >> 3;

    const float* row = oaw + (size_t)bq * 96;
    const float rx = refp[(size_t)bq * 2 + 0] * (float)WIMG;
    const float ry = refp[(size_t)bq * 2 + 1] * (float)HIMG;

    const float4 aw4 = *(const float4*)(row + 64 + h * 4);
    const float mx = fmaxf(fmaxf(aw4.x, aw4.y), fmaxf(aw4.z, aw4.w));
    const float e0 = __expf(aw4.x - mx), e1 = __expf(aw4.y - mx);
    const float e2 = __expf(aw4.z - mx), e3 = __expf(aw4.w - mx);
    const float inv = 1.f / (e0 + e1 + e2 + e3);
    const float w4[4] = {e0 * inv, e1 * inv, e2 * inv, e3 * inv};

    const int b = bq / Lq_;
    const u16* vb = val + (size_t)b * LIN * C_ + h * 32 + c0;

    float acc[8] = {};
#pragma unroll
    for (int p = 0; p < NP_; ++p) {
        const float2 off = *(const float2*)(row + (h * 4 + p) * 2);
        const float x = rx + off.x - 0.5f;
        const float y = ry + off.y - 0.5f;
        const float xf = floorf(x), yf = floorf(y);
        const float lx = x - xf, ly = y - yf;
        const int x0 = (int)xf, y0 = (int)yf;
        const float wp = w4[p];
        const float w00 = wp * (1.f - lx) * (1.f - ly);
        const float w10 = wp * lx * (1.f - ly);
        const float w01 = wp * (1.f - lx) * ly;
        const float w11 = wp * lx * ly;

#pragma unroll
        for (int c = 0; c < 4; ++c) {
            const int xi = x0 + (c & 1);
            const int yi = y0 + (c >> 1);
            const float wc = (c == 0) ? w00 : (c == 1) ? w10 : (c == 2) ? w01 : w11;
            const bool v = ((unsigned)xi < (unsigned)WIMG) & ((unsigned)yi < (unsigned)HIMG);
            const int idx = v ? (yi * WIMG + xi) : 0;
            const float w = v ? wc : 0.f;
            const short8 d = *(const short8*)(vb + (size_t)idx * C_);
#pragma unroll
            for (int j = 0; j < 8; ++j)
                acc[j] = fmaf(w, bf2f(((const u16*)&d)[j]), acc[j]);
        }
    }

    union { short8 s; u16 u[8]; } o;
#pragma unroll
    for (int j = 0; j < 8; ++j) o.u[j] = f2bf(acc[j]);
    *(short8*)(attn + (size_t)bq * C_ + h * 32 + c0) = o.s;
}

// ---------------------------------------------------------------------------
extern "C" void kernel_launch(void* const* d_in, const int* in_sizes, int n_in,
                              void* d_out, int out_size, void* d_ws, size_t ws_size,
                              hipStream_t stream)
{
    const float* query = (const float*)d_in[0];
    const float* src   = (const float*)d_in[1];
    const float* refp  = (const float*)d_in[2];
    const float* W_off = (const float*)d_in[5];
    const float* b_off = (const float*)d_in[6];
    const float* W_aw  = (const float*)d_in[7];
    const float* b_aw  = (const float*)d_in[8];
    const float* W_val = (const float*)d_in[9];
    const float* b_val = (const float*)d_in[10];
    const float* W_out = (const float*)d_in[11];
    const float* b_out = (const float*)d_in[12];
    const float* g1    = (const float*)d_in[13];
    const float* be1   = (const float*)d_in[14];
    const float* W1    = (const float*)d_in[15];
    const float* b1    = (const float*)d_in[16];
    const float* W2    = (const float*)d_in[17];
    const float* b2    = (const float*)d_in[18];
    const float* g2    = (const float*)d_in[19];
    const float* be2   = (const float*)d_in[20];
    float* out = (float*)d_out;

    char* ws = (char*)d_ws;

    // Workspace (~319 MB of ~327.7 MB):
    u16*  val  = (u16*)(ws + 0);            // 40.96 MB
    float* oaw = (float*)(ws + 40960000);   // 30.72 MB
    u16*  attn = (u16*)(ws + 71680000);     // 40.96 MB
    u16*  q1b  = (u16*)(ws + 112640000);    // 40.96 MB (swizzled layout)
    u16*  h    = (u16*)(ws + 153600000);    // 163.84 MB
    u16*  Wvs  = (u16*)(ws + 317440000);
    u16*  Wos  = (u16*)(ws + 317440000 + 131072);
    u16*  W1g  = (u16*)(ws + 317440000 + 262144);
    u16*  W2g  = (u16*)(ws + 317440000 + 786432);
    u16*  Woa  = (u16*)(ws + 317440000 + 1310720);
    float* boa = (float*)(ws + 317440000 + 1376256);

    prep_all<<<2689, 256, 0, stream>>>(W_val, W_out, W1, W2, W_off, W_aw,
                                       b_off, b_aw, Wvs, Wos, W1g, W2g,
                                       Woa, boa);

    // value = src @ W_val + b_val  (A f32) -> bf16 linear
    gemm256<0, 0><<<dim3(625, 1), 512, 0, stream>>>(
        src, Wvs, b_val, nullptr, nullptr, nullptr, val, 256, 256);

    // oaw = query @ [W_off|W_aw] + bias  (N padded 96->128)
    gemm_oaw<<<dim3(1, 625), 256, 0, stream>>>(
        query, Woa, boa, oaw, B_ * Lq_, 256, 96, 96);

    // bilinear sampling + softmax combine -> attn bf16 linear
    sample_attn<<<10000, 256, 0, stream>>>(val, oaw, refp, attn);

    // q1 = LN(query + attn @ W_out + b_out) -> q1b bf16 (swizzled)
    gemm256<1, 2><<<dim3(625, 1), 512, 0, stream>>>(
        attn, Wos, b_out, query, g1, be1, q1b, 256, 256);

    // h = relu(q1 @ W1 + b1)  (A = q1b pre-swizzled) -> bf16 linear, N=1024
    gemm256<2, 1><<<dim3(625, 4), 512, 0, stream>>>(
        q1b, W1g, b1, nullptr, nullptr, nullptr, h, 256, 1024);

    // out = LN2(q1 + h @ W2 + b2) -> f32 (K=1024, resid from swizzled q1b)
    gemm256<1, 3><<<dim3(625, 1), 512, 0, stream>>>(
        h, W2g, b2, q1b, g2, be2, out, 1024, 256);
}

// Round 12
// 321.279 us; speedup vs baseline: 1.1217x; 1.1217x over previous
//
#include <hip/hip_runtime.h>
#include <hip/hip_bf16.h>

typedef __hip_bfloat16 bf16;
typedef unsigned short u16;
typedef short short8 __attribute__((ext_vector_type(8)));
typedef float f32x4 __attribute__((ext_vector_type(4)));

static constexpr int B_   = 8;
static constexpr int Lq_  = 10000;
static constexpr int C_   = 256;
static constexpr int NH_  = 8;
static constexpr int NP_  = 4;
static constexpr int HIMG = 100;
static constexpr int WIMG = 100;
static constexpr int LIN  = 10000;   // H*W

__device__ __forceinline__ u16 f2bf(float x) {
    union { bf16 b; u16 u; } cv; cv.b = __float2bfloat16(x); return cv.u;
}
__device__ __forceinline__ float bf2f(u16 u) {
    return __uint_as_float((unsigned)u << 16);
}

// Async global -> LDS, 16 B per lane. LDS dest wave-uniform; HW writes
// base + lane*16 (guide §5 m104).
__device__ __forceinline__ void gl_lds16(const void* g, void* l) {
    __builtin_amdgcn_global_load_lds(
        (const __attribute__((address_space(1))) void*)g,
        (__attribute__((address_space(3))) void*)l, 16, 0, 0);
}
__device__ __forceinline__ void drain_barrier() {
    asm volatile("s_waitcnt vmcnt(0) lgkmcnt(0)" ::: "memory");
    __builtin_amdgcn_s_barrier();
}
#define VMW(N) asm volatile("s_waitcnt vmcnt(" #N ")" ::: "memory")
#define LKW0() asm volatile("s_waitcnt lgkmcnt(0)" ::: "memory")
#define BAR()  __builtin_amdgcn_s_barrier()

// Pair-row packed LDS tile format (R10-verified, <=2-way bank conflicts):
// storage si -> pr=si>>6, h=(si>>5)&1, e=si&31; holds logical
// (row = 2pr+h, col = e ^ ((pr&3)<<3)). 128 B storage rows -> frag b128
// reads spread over all 32 banks (2 lanes/bank).

// ---------------------------------------------------------------------------
// gemm256 v3 — BK=32, 52 KB LDS -> 2 blocks/CU (the fix). 128x256 tile,
// 8 waves (2m x 4n), 2-phase dbuf with per-step drains; cross-block wave
// overlap hides the drain latency (m114 mechanism, R4-verified).
// B pre-packed per 32-k tile (verbatim gl_lds). A packed on the fly.
// AMODE: 0 = A f32 (reg-stage+convert)   1 = A bf16 linear (gl_lds)
// EPI:   0 = bias -> bf16 linear         2 = LN(f32 resid) -> swizzled q1b
// ---------------------------------------------------------------------------
template <int AMODE, int EPI>
__global__ __launch_bounds__(512, 4) void gemm256(
    const void* __restrict__ Av, const u16* __restrict__ Bg,
    const float* __restrict__ bias, const float* __restrict__ resid,
    const float* __restrict__ gw, const float* __restrict__ bw,
    u16* __restrict__ Co, int K, int ldc)
{
    __shared__ __align__(16) u16 At[2][128 * 32];   // 16 KB
    __shared__ __align__(16) u16 Bt[2][256 * 32];   // 32 KB
    __shared__ float red[2][128][4];                //  4 KB

    const int tid  = threadIdx.x;
    const int lane = tid & 63;
    const int w    = tid >> 6;
    const int wm   = w >> 2, wn = w & 3;
    const int m0   = blockIdx.x * 128;

    f32x4 acc[4][4];
#pragma unroll
    for (int i = 0; i < 4; ++i)
#pragma unroll
        for (int j = 0; j < 4; ++j) acc[i][j] = f32x4{0.f, 0.f, 0.f, 0.f};

    auto stageA = [&](int t) {
        const int kt = t << 5;
        if constexpr (AMODE == 0) {
            // thread covers storage si = tid*8
            const int pr = tid >> 3;
            const int h  = (tid >> 2) & 1;
            const int ge = (tid & 3) ^ (pr & 3);
            const float* s = (const float*)Av
                + (size_t)(m0 + (pr << 1) + h) * K + kt + ge * 8;
            const float4 v0 = *(const float4*)(s + 0);
            const float4 v1 = *(const float4*)(s + 4);
            union { short8 s8; u16 u[8]; } g;
            g.u[0]=f2bf(v0.x); g.u[1]=f2bf(v0.y); g.u[2]=f2bf(v0.z); g.u[3]=f2bf(v0.w);
            g.u[4]=f2bf(v1.x); g.u[5]=f2bf(v1.y); g.u[6]=f2bf(v1.z); g.u[7]=f2bf(v1.w);
            *(short8*)&At[t & 1][tid * 8] = g.s8;
        } else {
            // wave covers storage si = w*512 + lane*8 (one gl_lds)
            const int pr = w * 8 + (lane >> 3);
            const int h  = (lane >> 2) & 1;
            const int ge = (lane & 3) ^ (pr & 3);
            gl_lds16((const u16*)Av + (size_t)(m0 + (pr << 1) + h) * K + kt + ge * 8,
                     &At[t & 1][w * 512]);
        }
    };
    auto stageB = [&](int t) {
        // Bg pre-packed: tile t is 8192 contiguous elems; verbatim copy
#pragma unroll
        for (int i = 0; i < 2; ++i) {
            const int sb = w * 1024 + i * 512;
            gl_lds16(Bg + (size_t)t * 8192 + sb + lane * 8, &Bt[t & 1][sb]);
        }
    };
    auto compute = [&](int t) {
        const u16* a = At[t & 1];
        const u16* b = Bt[t & 1];
        const int ko = (lane >> 4) << 3;
        short8 bfr[4];
#pragma unroll
        for (int n = 0; n < 4; ++n) {
            const int nr = wn * 64 + n * 16 + (lane & 15);
            const int pr = nr >> 1;
            bfr[n] = *(const short8*)&b[pr * 64 + (nr & 1) * 32 + (ko ^ ((pr & 3) << 3))];
        }
#pragma unroll
        for (int m = 0; m < 4; ++m) {
            const int ar = wm * 64 + m * 16 + (lane & 15);
            const int pa = ar >> 1;
            const short8 af = *(const short8*)
                &a[pa * 64 + (ar & 1) * 32 + (ko ^ ((pa & 3) << 3))];
#pragma unroll
            for (int n = 0; n < 4; ++n)
                acc[m][n] = __builtin_amdgcn_mfma_f32_16x16x32_bf16(
                    af, bfr[n], acc[m][n], 0, 0, 0);
        }
    };

    stageA(0); stageB(0);
    drain_barrier();
    const int nt = K >> 5;
    for (int t = 0; t < nt; ++t) {
        if (t + 1 < nt) { stageA(t + 1); stageB(t + 1); }
        compute(t);
        drain_barrier();
    }

    float bcol[4], gcol[4], becol[4];
#pragma unroll
    for (int n = 0; n < 4; ++n) {
        const int col = wn * 64 + n * 16 + (lane & 15);
        bcol[n] = bias[col];
        if (EPI == 2) { gcol[n] = gw[col]; becol[n] = bw[col]; }
    }

    if constexpr (EPI == 0) {
#pragma unroll
        for (int m = 0; m < 4; ++m)
#pragma unroll
            for (int r = 0; r < 4; ++r) {
                const int lr = wm * 64 + m * 16 + (lane >> 4) * 4 + r;
#pragma unroll
                for (int n = 0; n < 4; ++n) {
                    const int col = wn * 64 + n * 16 + (lane & 15);
                    Co[(size_t)(m0 + lr) * ldc + col] = f2bf(acc[m][n][r] + bcol[n]);
                }
            }
    } else {
        float s[4][4], s2[4][4];
#pragma unroll
        for (int m = 0; m < 4; ++m)
#pragma unroll
            for (int r = 0; r < 4; ++r) {
                const int lr = wm * 64 + m * 16 + (lane >> 4) * 4 + r;
                float ps = 0.f, ps2 = 0.f;
#pragma unroll
                for (int n = 0; n < 4; ++n) {
                    const int col = wn * 64 + n * 16 + (lane & 15);
                    float v = acc[m][n][r] + bcol[n]
                            + ((const float*)resid)[(size_t)(m0 + lr) * 256 + col];
                    acc[m][n][r] = v;
                    ps += v; ps2 += v * v;
                }
#pragma unroll
                for (int o = 1; o < 16; o <<= 1) {
                    ps  += __shfl_xor(ps,  o);
                    ps2 += __shfl_xor(ps2, o);
                }
                s[m][r] = ps; s2[m][r] = ps2;
            }
        if ((lane & 15) == 0) {
#pragma unroll
            for (int m = 0; m < 4; ++m)
#pragma unroll
                for (int r = 0; r < 4; ++r) {
                    const int lr = wm * 64 + m * 16 + (lane >> 4) * 4 + r;
                    red[0][lr][wn] = s[m][r];
                    red[1][lr][wn] = s2[m][r];
                }
        }
        __syncthreads();
        if (tid < 128) {
            const float ss  = red[0][tid][0] + red[0][tid][1] + red[0][tid][2] + red[0][tid][3];
            const float ss2 = red[1][tid][0] + red[1][tid][1] + red[1][tid][2] + red[1][tid][3];
            const float mean = ss * (1.f / 256.f);
            const float var  = fmaxf(ss2 * (1.f / 256.f) - mean * mean, 0.f);
            red[0][tid][0] = mean;
            red[1][tid][0] = rsqrtf(var + 1e-5f);
        }
        __syncthreads();
#pragma unroll
        for (int m = 0; m < 4; ++m)
#pragma unroll
            for (int r = 0; r < 4; ++r) {
                const int lr = wm * 64 + m * 16 + (lane >> 4) * 4 + r;
                const float mean = red[0][lr][0];
                const float rstd = red[1][lr][0];
#pragma unroll
                for (int n = 0; n < 4; ++n) {
                    const int col = wn * 64 + n * 16 + (lane & 15);
                    const float o = (acc[m][n][r] - mean) * rstd * gcol[n] + becol[n];
                    // q1b format: 64-slice XOR (lr&7)<<3
                    Co[(size_t)(m0 + lr) * 256 + (col ^ ((lr & 7) << 3))] = f2bf(o);
                }
            }
    }
}

// ---------------------------------------------------------------------------
// ffn_fused — R7 v2 counted-vmcnt schedule, verbatim (166 us measured).
// ---------------------------------------------------------------------------
__global__ __launch_bounds__(512) void ffn_fused(
    const u16* __restrict__ q1b, const u16* __restrict__ W1s,
    const u16* __restrict__ W2s, const float* __restrict__ b1,
    const float* __restrict__ b2, const float* __restrict__ g2,
    const float* __restrict__ be2, float* __restrict__ out)
{
    __shared__ __align__(16) u16 As[128 * 256];
    __shared__ __align__(16) u16 Hs[128 * 136];
    __shared__ __align__(16) u16 B1t[3][128 * 32];
    __shared__ __align__(16) u16 B2t[2][256 * 32];
    float (*red)[128][4] = (float (*)[128][4])Hs;

    const int tid  = threadIdx.x;
    const int lane = tid & 63;
    const int w    = tid >> 6;
    const int wm   = w >> 2, wn = w & 3;
    const int m0   = blockIdx.x * 128;

    f32x4 acc2[4][4];
#pragma unroll
    for (int i = 0; i < 4; ++i)
#pragma unroll
        for (int j = 0; j < 4; ++j) acc2[i][j] = f32x4{0.f, 0.f, 0.f, 0.f};

    auto issueB1 = [&](int c, int t, int buf) {
        const int rb  = w * 16;
        const int row = rb + (lane >> 2);
        gl_lds16(W1s + (size_t)(c * 128 + row) * 256 + t * 32 + (lane & 3) * 8,
                 &B1t[buf][rb * 32]);
    };
    auto issueB2 = [&](int c, int u, int buf) {
#pragma unroll
        for (int i = 0; i < 2; ++i) {
            const int rb  = i * 128 + w * 16;
            const int row = rb + (lane >> 2);
            gl_lds16(W2s + (size_t)row * 1024 + c * 128 + u * 32 + (lane & 3) * 8,
                     &B2t[buf][rb * 32]);
        }
    };

#pragma unroll
    for (int i = 0; i < 8; ++i) {
        const int rb = w * 16 + i * 2;
        gl_lds16(q1b + (size_t)(m0 + rb + (lane >> 5)) * 256 + (lane & 31) * 8,
                 &As[rb * 256]);
    }
    issueB1(0, 0, 0); issueB1(0, 1, 1); issueB1(0, 2, 2);
    VMW(2); BAR();

    for (int c = 0; c < 8; ++c) {
        f32x4 acc1[4][2];
#pragma unroll
        for (int i = 0; i < 4; ++i)
#pragma unroll
            for (int j = 0; j < 2; ++j) acc1[i][j] = f32x4{0.f, 0.f, 0.f, 0.f};

        auto g1 = [&](int t, int buf) {
            const u16* bb = B1t[buf];
            const int ko = (lane >> 4) << 3;
            short8 bfr[2];
#pragma unroll
            for (int n = 0; n < 2; ++n) {
                const int nr = wn * 32 + n * 16 + (lane & 15);
                bfr[n] = *(const short8*)&bb[nr * 32 + (ko ^ ((nr & 3) << 3))];
            }
#pragma unroll
            for (int m = 0; m < 4; ++m) {
                const int ar = wm * 64 + m * 16 + (lane & 15);
                const short8 af = *(const short8*)
                    &As[ar * 256 + ((t * 32 + ko) ^ ((ar & 7) << 3))];
#pragma unroll
                for (int n = 0; n < 2; ++n)
                    acc1[m][n] = __builtin_amdgcn_mfma_f32_16x16x32_bf16(
                        af, bfr[n], acc1[m][n], 0, 0, 0);
            }
        };
        auto g2s = [&](int u, int buf) {
            const u16* bb = B2t[buf];
            const int ko = (lane >> 4) << 3;
            short8 bfr[4];
#pragma unroll
            for (int n = 0; n < 4; ++n) {
                const int nr = wn * 64 + n * 16 + (lane & 15);
                bfr[n] = *(const short8*)&bb[nr * 32 + (ko ^ ((nr & 3) << 3))];
            }
#pragma unroll
            for (int m = 0; m < 4; ++m) {
                const int hr = wm * 64 + m * 16 + (lane & 15);
                const short8 af = *(const short8*)&Hs[hr * 136 + u * 32 + ko];
#pragma unroll
                for (int n = 0; n < 4; ++n)
                    acc2[m][n] = __builtin_amdgcn_mfma_f32_16x16x32_bf16(
                        af, bfr[n], acc2[m][n], 0, 0, 0);
            }
        };

        g1(0, 0);
        if (c == 0) { VMW(1); } else { VMW(3); }
        BAR();
        issueB1(c, 3, 0); g1(1, 1); VMW(1); BAR();
        issueB1(c, 4, 1); g1(2, 2); VMW(1); BAR();
        issueB1(c, 5, 2); g1(3, 0); VMW(1); BAR();
        issueB1(c, 6, 0); g1(4, 1); VMW(1); BAR();
        issueB1(c, 7, 1); g1(5, 2); VMW(1); BAR();
        issueB2(c, 0, 0); g1(6, 0); VMW(2); BAR();
        issueB2(c, 1, 1); g1(7, 1); VMW(2); BAR();

#pragma unroll
        for (int n = 0; n < 2; ++n) {
            const int col = wn * 32 + n * 16 + (lane & 15);
            const float bb = b1[c * 128 + col];
#pragma unroll
            for (int m = 0; m < 4; ++m)
#pragma unroll
                for (int r = 0; r < 4; ++r) {
                    const int row = wm * 64 + m * 16 + (lane >> 4) * 4 + r;
                    Hs[row * 136 + col] = f2bf(fmaxf(acc1[m][n][r] + bb, 0.f));
                }
        }
        LKW0(); BAR();

        issueB1(c + 1, 0, 0);                    g2s(0, 0); VMW(1); BAR();
        issueB2(c, 2, 0); issueB1(c + 1, 1, 1);  g2s(1, 1); VMW(1); BAR();
        issueB2(c, 3, 1); issueB1(c + 1, 2, 2);  g2s(2, 0); VMW(1); BAR();
        g2s(3, 1); VMW(6); BAR();
    }
    asm volatile("s_waitcnt vmcnt(0)" ::: "memory");
    BAR();

    float bcol[4], gcol[4], becol[4];
#pragma unroll
    for (int n = 0; n < 4; ++n) {
        const int col = wn * 64 + n * 16 + (lane & 15);
        bcol[n] = b2[col]; gcol[n] = g2[col]; becol[n] = be2[col];
    }
    float s[4][4], s2[4][4];
#pragma unroll
    for (int m = 0; m < 4; ++m)
#pragma unroll
        for (int r = 0; r < 4; ++r) {
            const int lr = wm * 64 + m * 16 + (lane >> 4) * 4 + r;
            float ps = 0.f, ps2 = 0.f;
#pragma unroll
            for (int n = 0; n < 4; ++n) {
                const int col = wn * 64 + n * 16 + (lane & 15);
                const float q = bf2f(As[lr * 256 + (col ^ ((lr & 7) << 3))]);
                const float v = acc2[m][n][r] + bcol[n] + q;
                acc2[m][n][r] = v;
                ps += v; ps2 += v * v;
            }
#pragma unroll
            for (int o = 1; o < 16; o <<= 1) {
                ps  += __shfl_xor(ps,  o);
                ps2 += __shfl_xor(ps2, o);
            }
            s[m][r] = ps; s2[m][r] = ps2;
        }
    if ((lane & 15) == 0) {
#pragma unroll
        for (int m = 0; m < 4; ++m)
#pragma unroll
            for (int r = 0; r < 4; ++r) {
                const int lr = wm * 64 + m * 16 + (lane >> 4) * 4 + r;
                red[0][lr][wn] = s[m][r];
                red[1][lr][wn] = s2[m][r];
            }
    }
    __syncthreads();
    if (tid < 128) {
        const float ss  = red[0][tid][0] + red[0][tid][1] + red[0][tid][2] + red[0][tid][3];
        const float ss2 = red[1][tid][0] + red[1][tid][1] + red[1][tid][2] + red[1][tid][3];
        const float mean = ss * (1.f / 256.f);
        const float var  = fmaxf(ss2 * (1.f / 256.f) - mean * mean, 0.f);
        red[0][tid][0] = mean;
        red[1][tid][0] = rsqrtf(var + 1e-5f);
    }
    __syncthreads();
#pragma unroll
    for (int m = 0; m < 4; ++m)
#pragma unroll
        for (int r = 0; r < 4; ++r) {
            const int lr = wm * 64 + m * 16 + (lane >> 4) * 4 + r;
            const float mean = red[0][lr][0];
            const float rstd = red[1][lr][0];
#pragma unroll
            for (int n = 0; n < 4; ++n) {
                const int col = wn * 64 + n * 16 + (lane & 15);
                out[(size_t)(m0 + lr) * 256 + col] =
                    (acc2[m][n][r] - mean) * rstd * gcol[n] + becol[n];
            }
        }
}

// ---------------------------------------------------------------------------
// 4-wave 128x128 MFMA GEMM — oaw projection only (unchanged).
// ---------------------------------------------------------------------------
__global__ __launch_bounds__(256) void gemm_oaw(
    const float* __restrict__ Av, const u16* __restrict__ Bt,
    const float* __restrict__ bias, float* __restrict__ C,
    int M, int K, int Nreal, int ldc)
{
    __shared__ __align__(16) u16 Asl[2][128 * 32];
    __shared__ __align__(16) u16 Bsl[2][128 * 32];

    const int tid  = threadIdx.x;
    const int lane = tid & 63;
    const int w    = tid >> 6;
    const int wr   = (w >> 1) * 64;
    const int wc   = (w & 1) * 64;
    const int m0   = blockIdx.y * 128;
    const int n0   = blockIdx.x * 128;

    const int srow = lane >> 2;
    const int scol = (lane & 3) << 3;
    const u16* bG = Bt + (size_t)(n0 + w * 32 + srow) * K + scol;
    const size_t rstep16 = (size_t)16 * K;

    const int ar  = lane >> 3;
    const int ac  = (lane & 7) << 2;
    const float* aGf = Av + (size_t)(m0 + w * 32 + ar) * K + ac;

    const int aRoff = (wr + (lane & 15)) * 32 + (lane >> 4) * 8;
    const int bRoff = (wc + (lane & 15)) * 32 + (lane >> 4) * 8;

    f32x4 acc[4][4];
#pragma unroll
    for (int i = 0; i < 4; ++i)
#pragma unroll
        for (int j = 0; j < 4; ++j) acc[i][j] = f32x4{0.f, 0.f, 0.f, 0.f};

    float4 a4[4];
    const int nt = K >> 5;

#pragma unroll
    for (int rep = 0; rep < 4; ++rep)
        a4[rep] = *(const float4*)(aGf + (size_t)(rep * 8) * K);
#pragma unroll
    for (int rep = 0; rep < 4; ++rep) {
        ushort4 v{f2bf(a4[rep].x), f2bf(a4[rep].y), f2bf(a4[rep].z), f2bf(a4[rep].w)};
        *(ushort4*)&Asl[0][(w * 32 + rep * 8 + ar) * 32 + ac] = v;
    }
    gl_lds16(bG, &Bsl[0][(w * 32) * 32]);
    gl_lds16(bG + rstep16, &Bsl[0][(w * 32 + 16) * 32]);
    drain_barrier();

    for (int t = 0; t < nt; ++t) {
        const int cur = t & 1, nxt = cur ^ 1;
        const int k0n = (t + 1) << 5;
        const bool has_next = (t + 1 < nt);
        if (has_next) {
#pragma unroll
            for (int rep = 0; rep < 4; ++rep)
                a4[rep] = *(const float4*)(aGf + k0n + (size_t)(rep * 8) * K);
            gl_lds16(bG + k0n, &Bsl[nxt][(w * 32) * 32]);
            gl_lds16(bG + k0n + rstep16, &Bsl[nxt][(w * 32 + 16) * 32]);
        }
        short8 af[4], bfr[4];
#pragma unroll
        for (int m = 0; m < 4; ++m) af[m]  = *(const short8*)&Asl[cur][aRoff + m * 16 * 32];
#pragma unroll
        for (int n = 0; n < 4; ++n) bfr[n] = *(const short8*)&Bsl[cur][bRoff + n * 16 * 32];
#pragma unroll
        for (int m = 0; m < 4; ++m)
#pragma unroll
            for (int n = 0; n < 4; ++n)
                acc[m][n] = __builtin_amdgcn_mfma_f32_16x16x32_bf16(
                    af[m], bfr[n], acc[m][n], 0, 0, 0);
        if (has_next) {
#pragma unroll
            for (int rep = 0; rep < 4; ++rep) {
                ushort4 v{f2bf(a4[rep].x), f2bf(a4[rep].y), f2bf(a4[rep].z), f2bf(a4[rep].w)};
                *(ushort4*)&Asl[nxt][(w * 32 + rep * 8 + ar) * 32 + ac] = v;
            }
        }
        drain_barrier();
    }

#pragma unroll
    for (int n = 0; n < 4; ++n) {
        const int gc = n0 + wc + n * 16 + (lane & 15);
        if (gc >= Nreal) continue;
        const float bv = bias[gc];
        const int gr0 = m0 + wr + (lane >> 4) * 4;
#pragma unroll
        for (int m = 0; m < 4; ++m)
#pragma unroll
            for (int r = 0; r < 4; ++r)
                C[(size_t)(gr0 + m * 16 + r) * ldc + gc] = acc[m][n][r] + bv;
    }
}

// ---------------------------------------------------------------------------
// Weight prep.
// Wvs/Wos: pair-row packed per 32-k tile (gemm256 v3 format):
//   i -> tile t=i>>13, si=i&8191, pr=si>>6, h=(si>>5)&1, e=si&31;
//   n=2pr+h; k = t*32 + (e ^ ((pr&3)<<3)); Bg[i] = W[k][n].
// W1s: [1024n][256k], XOR (n&3)<<3  (ffn_fused format, R7).
// W2s: [256n][1024k], XOR (n&3)<<3  (ffn_fused format, R7).
// Woa: linear [128][256] + padded bias (gemm_oaw, unchanged).
// ---------------------------------------------------------------------------
__global__ __launch_bounds__(256) void prep_all(
    const float* __restrict__ Wv, const float* __restrict__ Wo,
    const float* __restrict__ W1, const float* __restrict__ W2,
    const float* __restrict__ Woff, const float* __restrict__ Waw,
    const float* __restrict__ boff, const float* __restrict__ baw,
    u16* __restrict__ Wvs, u16* __restrict__ Wos,
    u16* __restrict__ W1s, u16* __restrict__ W2s,
    u16* __restrict__ Woa, float* __restrict__ boa)
{
    const int idx = blockIdx.x * 256 + threadIdx.x;
    if (idx < 65536) {
        const int t = idx >> 13, si = idx & 8191;
        const int pr = si >> 6, h = (si >> 5) & 1, e = si & 31;
        const int n = (pr << 1) | h;
        const int k = t * 32 + (e ^ ((pr & 3) << 3));
        Wvs[idx] = f2bf(Wv[(size_t)k * 256 + n]);
    } else if (idx < 131072) {
        const int i = idx - 65536;
        const int t = i >> 13, si = i & 8191;
        const int pr = si >> 6, h = (si >> 5) & 1, e = si & 31;
        const int n = (pr << 1) | h;
        const int k = t * 32 + (e ^ ((pr & 3) << 3));
        Wos[i] = f2bf(Wo[(size_t)k * 256 + n]);
    } else if (idx < 393216) {
        const int i = idx - 131072, n = i >> 8, kd = i & 255;
        W1s[i] = f2bf(W1[(size_t)(kd ^ ((n & 3) << 3)) * 1024 + n]);
    } else if (idx < 655360) {
        const int i = idx - 393216, n = i >> 10, kd = i & 1023;
        W2s[i] = f2bf(W2[(size_t)(kd ^ ((n & 3) << 3)) * 256 + n]);
    } else if (idx < 688128) {
        const int i = idx - 655360, n = i >> 8, k = i & 255;
        float v = 0.f;
        if (n < 64)      v = Woff[(size_t)k * 64 + n];
        else if (n < 96) v = Waw[(size_t)k * 32 + (n - 64)];
        Woa[i] = f2bf(v);
    } else if (idx < 688256) {
        const int i = idx - 688128;
        boa[i] = (i < 64) ? boff[i] : (i < 96 ? baw[i - 64] : 0.f);
    }
}

// ---------------------------------------------------------------------------
// Bilinear sampling + attention-weight combine (unchanged).
// ---------------------------------------------------------------------------
__global__ __launch_bounds__(256) void sample_attn(
    const u16* __restrict__ val, const float* __restrict__ oaw,
    const float* __restrict__ refp, u16* __restrict__ attn)
{
    const int t   = threadIdx.x;
    const int gid = blockIdx.x * 64 + (t >> 2);
    const int c0  = (t & 3) << 3;
    const int h   = gid & (NH_ - 1);
    const int bq  = gid >> 3;

    const float* row = oaw + (size_t)bq * 96;
    const float rx = refp[(size_t)bq * 2 + 0] * (float)WIMG;
    const float ry = refp[(size_t)bq * 2 + 1] * (float)HIMG;

    const float4 aw4 = *(const float4*)(row + 64 + h * 4);
    const float mx = fmaxf(fmaxf(aw4.x, aw4.y), fmaxf(aw4.z, aw4.w));
    const float e0 = __expf(aw4.x - mx), e1 = __expf(aw4.y - mx);
    const float e2 = __expf(aw4.z - mx), e3 = __expf(aw4.w - mx);
    const float inv = 1.f / (e0 + e1 + e2 + e3);
    const float w4[4] = {e0 * inv, e1 * inv, e2 * inv, e3 * inv};

    const int b = bq / Lq_;
    const u16* vb = val + (size_t)b * LIN * C_ + h * 32 + c0;

    float acc[8] = {};
#pragma unroll
    for (int p = 0; p < NP_; ++p) {
        const float2 off = *(const float2*)(row + (h * 4 + p) * 2);
        const float x = rx + off.x - 0.5f;
        const float y = ry + off.y - 0.5f;
        const float xf = floorf(x), yf = floorf(y);
        const float lx = x - xf, ly = y - yf;
        const int x0 = (int)xf, y0 = (int)yf;
        const float wp = w4[p];
        const float w00 = wp * (1.f - lx) * (1.f - ly);
        const float w10 = wp * lx * (1.f - ly);
        const float w01 = wp * (1.f - lx) * ly;
        const float w11 = wp * lx * ly;

#pragma unroll
        for (int c = 0; c < 4; ++c) {
            const int xi = x0 + (c & 1);
            const int yi = y0 + (c >> 1);
            const float wc = (c == 0) ? w00 : (c == 1) ? w10 : (c == 2) ? w01 : w11;
            const bool v = ((unsigned)xi < (unsigned)WIMG) & ((unsigned)yi < (unsigned)HIMG);
            const int idx = v ? (yi * WIMG + xi) : 0;
            const float w = v ? wc : 0.f;
            const short8 d = *(const short8*)(vb + (size_t)idx * C_);
#pragma unroll
            for (int j = 0; j < 8; ++j)
                acc[j] = fmaf(w, bf2f(((const u16*)&d)[j]), acc[j]);
        }
    }

    union { short8 s; u16 u[8]; } o;
#pragma unroll
    for (int j = 0; j < 8; ++j) o.u[j] = f2bf(acc[j]);
    *(short8*)(attn + (size_t)bq * C_ + h * 32 + c0) = o.s;
}

// ---------------------------------------------------------------------------
extern "C" void kernel_launch(void* const* d_in, const int* in_sizes, int n_in,
                              void* d_out, int out_size, void* d_ws, size_t ws_size,
                              hipStream_t stream)
{
    const float* query = (const float*)d_in[0];
    const float* src   = (const float*)d_in[1];
    const float* refp  = (const float*)d_in[2];
    const float* W_off = (const float*)d_in[5];
    const float* b_off = (const float*)d_in[6];
    const float* W_aw  = (const float*)d_in[7];
    const float* b_aw  = (const float*)d_in[8];
    const float* W_val = (const float*)d_in[9];
    const float* b_val = (const float*)d_in[10];
    const float* W_out = (const float*)d_in[11];
    const float* b_out = (const float*)d_in[12];
    const float* g1    = (const float*)d_in[13];
    const float* be1   = (const float*)d_in[14];
    const float* W1    = (const float*)d_in[15];
    const float* b1    = (const float*)d_in[16];
    const float* W2    = (const float*)d_in[17];
    const float* b2    = (const float*)d_in[18];
    const float* g2    = (const float*)d_in[19];
    const float* be2   = (const float*)d_in[20];
    float* out = (float*)d_out;

    char* ws = (char*)d_ws;
    const int R = B_ * Lq_;  // 80000

    u16*  val  = (u16*)(ws + 0);           // 40.96 MB
    float* oaw = (float*)(ws + 40960000);  // 30.72 MB
    u16*  attn = (u16*)(ws + 71680000);    // 40.96 MB
    u16*  q1b  = (u16*)(ws + 112640000);   // 40.96 MB (swizzled layout)
    u16*  Wvs  = (u16*)(ws + 153600000);
    u16*  Wos  = (u16*)(ws + 153600000 + 131072);
    u16*  W1s  = (u16*)(ws + 153600000 + 262144);
    u16*  W2s  = (u16*)(ws + 153600000 + 786432);
    u16*  Woa  = (u16*)(ws + 153600000 + 1310720);
    float* boa = (float*)(ws + 153600000 + 1376256);

    prep_all<<<2689, 256, 0, stream>>>(W_val, W_out, W1, W2, W_off, W_aw,
                                       b_off, b_aw, Wvs, Wos, W1s, W2s,
                                       Woa, boa);

    // value = src @ W_val + b_val  (A f32) -> bf16 linear
    gemm256<0, 0><<<625, 512, 0, stream>>>(
        src, Wvs, b_val, nullptr, nullptr, nullptr, val, 256, 256);

    // oaw = query @ [W_off|W_aw] + bias  (N padded 96->128)
    gemm_oaw<<<dim3(1, 625), 256, 0, stream>>>(
        query, Woa, boa, oaw, R, 256, 96, 96);

    // bilinear sampling + softmax combine -> attn bf16 linear
    sample_attn<<<10000, 256, 0, stream>>>(val, oaw, refp, attn);

    // q1 = LN(query + attn @ W_out + b_out) -> q1b bf16 (swizzled)
    gemm256<1, 2><<<625, 512, 0, stream>>>(
        attn, Wos, b_out, query, g1, be1, q1b, 256, 256);

    // out = LN(q1 + FFN(q1)) -> f32 (R7 counted-vmcnt fused FFN)
    ffn_fused<<<625, 512, 0, stream>>>(q1b, W1s, W2s, b1, b2, g2, be2, out);
}